// Round 6
// baseline (411.923 us; speedup 1.0000x reference)
//
#include <hip/hip_runtime.h>
#include <stdint.h>

// ---------- types ----------
typedef __bf16 bf16x8 __attribute__((ext_vector_type(8)));
typedef __bf16 bf16x2 __attribute__((ext_vector_type(2)));
typedef float  f32x4  __attribute__((ext_vector_type(4)));
typedef unsigned short u16x4 __attribute__((ext_vector_type(4)));
typedef unsigned short u16x8 __attribute__((ext_vector_type(8)));

#define DEVI __device__ __forceinline__

// problem constants
constexpr int Bc = 4, Hc = 16, Ss = 2048, Dd = 128;
constexpr int BH = Bc * Hc;          // 64 heads
constexpr int BM = 256;              // q-rows per workgroup (4 waves x 64), mt=4 reuse
constexpr int MT = 4;                // 16-row fragments per wave
constexpr int BN = 32;               // keys per K-tile (double-buffered)
constexpr int NTIL = Ss / BN;        // 64 tiles
constexpr int LDP = 40;              // sP row stride (elems): 80 B, 16B-aligned rows
// scale folds in log2(e): e^(qk/128) = 2^((qk*log2e)/128)
constexpr float SCALE = 1.44269504088896340736f / 128.0f;

constexpr int TILE_B = BN * Dd * 2;  // 8192 B
constexpr int SK_OFF = 0;            // 2 buffers x 8 KiB
constexpr int SV_OFF = 2 * TILE_B;   // 2 buffers x 8 KiB
constexpr int SP_OFF = 4 * TILE_B;   // 256 x 40 bf16 P buffer (single; wave-private rows)
constexpr int LDS_BYTES = SP_OFF + BM * LDP * 2;   // 53248 B -> 2 WGs/CU (grid=2/CU exact)
static_assert(LDS_BYTES == 53248, "mt=4 config");

DEVI unsigned short f2bf_bits(float x) {
  unsigned u = __builtin_bit_cast(unsigned, x);
  u += 0x7fffu + ((u >> 16) & 1u);          // round-to-nearest-even
  return (unsigned short)(u >> 16);
}
DEVI __bf16 f2bf(float x) {
  unsigned short b = f2bf_bits(x);
  return __builtin_bit_cast(__bf16, b);
}

// hardware 2^x (v_exp_f32)
DEVI float exp2_hw(float x) { return __builtin_amdgcn_exp2f(x); }

// async global->LDS, 16B per lane; LDS dest = wave-uniform base + lane*16
DEVI void gload_lds16(const void* g, void* l) {
  __builtin_amdgcn_global_load_lds(
      (const __attribute__((address_space(1))) unsigned*)(uintptr_t)g,
      (__attribute__((address_space(3))) unsigned*)(unsigned)(uintptr_t)l,
      16, 0, 0);
}

// ---------------- fused pre-pass (unchanged, measured-good) ----------------
constexpr int LDT2 = 136;
__global__ void k_prep(const float* __restrict__ kin, __bf16* __restrict__ kout,
                       const float* __restrict__ v, __bf16* __restrict__ vt) {
  __shared__ __align__(16) unsigned short tile[64 * LDT2];
  const int bx = blockIdx.x;
  const int u = threadIdx.x;
  if (bx >= 2048) {
    constexpr int N4 = (BH * Ss * Dd) / 4;
    int i = (bx - 2048) * 256 + u;
    const int stride = 2048 * 256;
    #pragma unroll
    for (int it = 0; it < N4 / (2048 * 256); it++, i += stride) {
      float4 x = ((const float4*)kin)[i];
      ushort4 o;
      o.x = f2bf_bits(x.x); o.y = f2bf_bits(x.y);
      o.z = f2bf_bits(x.z); o.w = f2bf_bits(x.w);
      ((ushort4*)kout)[i] = o;
    }
    return;
  }
  const int bh = bx >> 5;
  const int s0 = (bx & 31) * 64;
  const float4* src = (const float4*)(v + ((size_t)bh * Ss + s0) * Dd);
  #pragma unroll
  for (int i = 0; i < 8; i++) {
    int f = i * 256 + u;
    int row = f >> 5;
    int c4 = (f & 31) << 2;
    float4 x = src[f];
    u16x4 o;
    o[0] = f2bf_bits(x.x); o[1] = f2bf_bits(x.y);
    o[2] = f2bf_bits(x.z); o[3] = f2bf_bits(x.w);
    *(u16x4*)&tile[row * LDT2 + c4] = o;
  }
  __syncthreads();
  const int so = u & 7;
  const int dq = u >> 3;
  u16x4 tin[8];
  #pragma unroll
  for (int i = 0; i < 8; i++)
    tin[i] = *(const u16x4*)&tile[(so * 8 + i) * LDT2 + dq * 4];
  #pragma unroll
  for (int j = 0; j < 4; j++) {
    u16x8 o;
    #pragma unroll
    for (int i = 0; i < 8; i++) o[i] = tin[i][j];
    *(u16x8*)(vt + ((size_t)bh * Dd + dq * 4 + j) * Ss + s0 + so * 8) = o;
  }
}

// ---------------- flash attention ----------------
// grid: 512 = 8 q-tiles x 64 heads. One-tile software pipeline on P:
// body t computes QK^T(t+1) and PV(t) -- independent MFMA streams, exp(t+1)
// VALU weaves between them. sP is wave-private (each wave reads only rows it
// wrote), so the P round-trip needs no barrier and no double buffer.
// K staged 2 tiles ahead, V staged 1 tile ahead; one barrier per body.
__launch_bounds__(256, 2)
__global__ void k_flash(const float* __restrict__ Q, const __bf16* __restrict__ Kb,
                        const __bf16* __restrict__ Vt, float* __restrict__ O) {
  __shared__ __align__(16) char lds[LDS_BYTES];
  unsigned short* sP = (unsigned short*)(lds + SP_OFF);

  const int tid = threadIdx.x;
  const int w = tid >> 6;           // wave 0..3, owns q-rows [64w, 64w+64)
  const int lane = tid & 63;
  const int quad = lane >> 4;
  const int l16 = lane & 15;

  const int bx = blockIdx.x;
  const int bh = bx & (BH - 1);
  const int q0 = (bx >> 6) * BM;

  // ---- Q fragments: fp32 load, scale, cvt to bf16, keep in regs ----
  bf16x8 qa[MT][4];
  {
    const float* qb = Q + ((size_t)bh * Ss + q0 + w * 64) * Dd;
    #pragma unroll
    for (int mt = 0; mt < MT; mt++)
      #pragma unroll
      for (int kk = 0; kk < 4; kk++) {
        const float* p = qb + (mt * 16 + l16) * Dd + kk * 32 + quad * 8;
        float4 a = ((const float4*)p)[0];
        float4 b = ((const float4*)p)[1];
        bf16x8 f;
        f[0] = f2bf(a.x * SCALE); f[1] = f2bf(a.y * SCALE);
        f[2] = f2bf(a.z * SCALE); f[3] = f2bf(a.w * SCALE);
        f[4] = f2bf(b.x * SCALE); f[5] = f2bf(b.y * SCALE);
        f[6] = f2bf(b.z * SCALE); f[7] = f2bf(b.w * SCALE);
        qa[mt][kk] = f;
      }
  }

  f32x4 acc[MT][8];
  #pragma unroll
  for (int mt = 0; mt < MT; mt++)
    #pragma unroll
    for (int dt = 0; dt < 8; dt++)
      acc[mt][dt] = (f32x4){0.f, 0.f, 0.f, 0.f};

  float lacc[MT] = {0.f, 0.f, 0.f, 0.f};

  const __bf16* kbh = Kb + (size_t)bh * Ss * Dd;   // [s][d]
  const __bf16* vbh = Vt + (size_t)bh * Ss * Dd;   // [d][s]

  // ---- per-wave stage assignment: waves 0,1 -> K frags; waves 2,3 -> V frags ----
  const char* gp[4];
  unsigned lo[4];
  int ginc;
  if (w < 2) {
    #pragma unroll
    for (int i = 0; i < 4; i++) {
      const int fk = w * 4 + i, kk = fk >> 1, nt = fk & 1;
      gp[i] = (const char*)(kbh + (size_t)(nt * 16 + l16) * Dd + kk * 32 + quad * 8);
      lo[i] = (unsigned)(SK_OFF + fk * 1024 + lane * 16);
    }
    ginc = BN * Dd * 2;             // next K tile: +32 rows
  } else {
    #pragma unroll
    for (int i = 0; i < 4; i++) {
      const int dt = (w - 2) * 4 + i;
      gp[i] = (const char*)(vbh + (size_t)(dt * 16 + l16) * Ss + quad * 8);
      lo[i] = (unsigned)(SV_OFF + dt * 1024 + lane * 16);
    }
    ginc = BN * 2;                  // next V tile: +32 columns
  }

  // ---- prologue staging: K0 -> Kbuf0, K1 -> Kbuf1, V0 -> Vbuf0 ----
  if (w < 2) {
    #pragma unroll
    for (int i = 0; i < 4; i++) { gload_lds16(gp[i], lds + lo[i]); gp[i] += ginc; }
    #pragma unroll
    for (int i = 0; i < 4; i++) { gload_lds16(gp[i], lds + lo[i] + TILE_B); gp[i] += ginc; }
  } else {
    #pragma unroll
    for (int i = 0; i < 4; i++) { gload_lds16(gp[i], lds + lo[i]); gp[i] += ginc; }
  }
  __syncthreads();

  // ---- prologue compute: tile 0 QK^T + exp + P write (no PV yet) ----
  {
    const char* bK = lds + SK_OFF;   // Kbuf0
    #pragma unroll
    for (int nt = 0; nt < 2; nt++) {
      f32x4 sc[MT];
      #pragma unroll
      for (int mt = 0; mt < MT; mt++) sc[mt] = (f32x4){0.f, 0.f, 0.f, 0.f};
      #pragma unroll
      for (int kk = 0; kk < 4; kk++) {
        bf16x8 bk = *(const bf16x8*)(bK + (kk * 2 + nt) * 1024 + lane * 16);
        #pragma unroll
        for (int mt = 0; mt < MT; mt++)
          sc[mt] = __builtin_amdgcn_mfma_f32_16x16x32_bf16(bk, qa[mt][kk], sc[mt], 0, 0, 0);
      }
      #pragma unroll
      for (int mt = 0; mt < MT; mt++) {
        float p0 = exp2_hw(sc[mt][0]);
        float p1 = exp2_hw(sc[mt][1]);
        float p2 = exp2_hw(sc[mt][2]);
        float p3 = exp2_hw(sc[mt][3]);
        lacc[mt] += (p0 + p1) + (p2 + p3);
        bf16x2 ba, bb;
        ba[0] = (__bf16)p0; ba[1] = (__bf16)p1;
        bb[0] = (__bf16)p2; bb[1] = (__bf16)p3;
        uint2 pw;
        pw.x = __builtin_bit_cast(unsigned, ba);
        pw.y = __builtin_bit_cast(unsigned, bb);
        *(uint2*)(sP + (w * 64 + mt * 16 + l16) * LDP + nt * 16 + quad * 4) = pw;
      }
    }
  }
  __syncthreads();   // Kbuf0 reads done before body-0 stages K2 into it

  // ---- main pipeline: body t does QK^T(t+1) + PV(t) ----
  for (int t = 0; t < NTIL - 1; t++) {
    const unsigned kst = (unsigned)(t & 1) * (unsigned)TILE_B;
    // stage K(t+2) -> Kbuf[t&1], V(t+1) -> Vbuf[(t+1)&1]
    if (w < 2) {
      if (t < NTIL - 2) {
        #pragma unroll
        for (int i = 0; i < 4; i++) { gload_lds16(gp[i], lds + lo[i] + kst); gp[i] += ginc; }
      }
    } else {
      #pragma unroll
      for (int i = 0; i < 4; i++) {
        gload_lds16(gp[i], lds + lo[i] + (kst ^ (unsigned)TILE_B)); gp[i] += ginc;
      }
    }
    const char* bK = lds + SK_OFF + (kst ^ (unsigned)TILE_B);  // Kbuf[(t+1)&1]
    const char* bV = lds + SV_OFF + kst;                        // Vbuf[t&1]

    // P(t) fragments (written last body / prologue; wave-private, DS in-order)
    bf16x8 pa[MT];
    #pragma unroll
    for (int mt = 0; mt < MT; mt++)
      pa[mt] = *(const bf16x8*)((const char*)sP +
               (size_t)((w * 64 + mt * 16 + l16) * LDP + quad * 8) * 2);

    // two phases: {QK^T(t+1) nt-half, PV(t) dt-half, exp nt-half}
    #pragma unroll
    for (int half = 0; half < 2; half++) {
      const int nt = half;
      f32x4 sc[MT];
      #pragma unroll
      for (int mt = 0; mt < MT; mt++) sc[mt] = (f32x4){0.f, 0.f, 0.f, 0.f};
      #pragma unroll
      for (int kk = 0; kk < 4; kk++) {
        bf16x8 bk = *(const bf16x8*)(bK + (kk * 2 + nt) * 1024 + lane * 16);
        #pragma unroll
        for (int mt = 0; mt < MT; mt++)
          sc[mt] = __builtin_amdgcn_mfma_f32_16x16x32_bf16(bk, qa[mt][kk], sc[mt], 0, 0, 0);
      }
      // PV half: independent of sc -> scheduler fills MFMA-latency + exp stalls
      #pragma unroll
      for (int dt = half * 4; dt < half * 4 + 4; dt++) {
        bf16x8 bv = *(const bf16x8*)(bV + dt * 1024 + lane * 16);
        #pragma unroll
        for (int mt = 0; mt < MT; mt++)
          acc[mt][dt] = __builtin_amdgcn_mfma_f32_16x16x32_bf16(pa[mt], bv, acc[mt][dt], 0, 0, 0);
      }
      // exp + pack + P(t+1) write (after pa was read: safe single-buffer)
      #pragma unroll
      for (int mt = 0; mt < MT; mt++) {
        float p0 = exp2_hw(sc[mt][0]);
        float p1 = exp2_hw(sc[mt][1]);
        float p2 = exp2_hw(sc[mt][2]);
        float p3 = exp2_hw(sc[mt][3]);
        lacc[mt] += (p0 + p1) + (p2 + p3);
        bf16x2 ba, bb;
        ba[0] = (__bf16)p0; ba[1] = (__bf16)p1;
        bb[0] = (__bf16)p2; bb[1] = (__bf16)p3;
        uint2 pw;
        pw.x = __builtin_bit_cast(unsigned, ba);
        pw.y = __builtin_bit_cast(unsigned, bb);
        *(uint2*)(sP + (w * 64 + mt * 16 + l16) * LDP + nt * 16 + quad * 4) = pw;
      }
    }

    __syncthreads();   // staged buffers ready; K/V parity flips
  }

  // ---- epilogue: PV(63) ----
  {
    const char* bV = lds + SV_OFF + TILE_B;   // Vbuf[63&1]
    bf16x8 pa[MT];
    #pragma unroll
    for (int mt = 0; mt < MT; mt++)
      pa[mt] = *(const bf16x8*)((const char*)sP +
               (size_t)((w * 64 + mt * 16 + l16) * LDP + quad * 8) * 2);
    #pragma unroll
    for (int dt = 0; dt < 8; dt++) {
      bf16x8 bv = *(const bf16x8*)(bV + dt * 1024 + lane * 16);
      #pragma unroll
      for (int mt = 0; mt < MT; mt++)
        acc[mt][dt] = __builtin_amdgcn_mfma_f32_16x16x32_bf16(pa[mt], bv, acc[mt][dt], 0, 0, 0);
    }
  }

  // ---- final l reduction: sum quads, broadcast to C-layout rows ----
  float inv_l[MT][4];
  #pragma unroll
  for (int mt = 0; mt < MT; mt++) {
    float l = lacc[mt];
    l += __shfl_xor(l, 16);
    l += __shfl_xor(l, 32);
    #pragma unroll
    for (int r = 0; r < 4; r++) {
      float lr = __shfl(l, (lane & 48) | (quad * 4 + r));
      inv_l[mt][r] = 1.0f / lr;
    }
  }

  // ---- epilogue: O / l ----
  float* ob = O + ((size_t)bh * Ss + q0 + w * 64) * Dd;
  #pragma unroll
  for (int mt = 0; mt < MT; mt++)
    #pragma unroll
    for (int r = 0; r < 4; r++) {
      const float inv = inv_l[mt][r];
      const int row = mt * 16 + quad * 4 + r;
      #pragma unroll
      for (int dt = 0; dt < 8; dt++)
        ob[row * Dd + dt * 16 + l16] = acc[mt][dt][r] * inv;
    }
}

extern "C" void kernel_launch(void* const* d_in, const int* in_sizes, int n_in,
                              void* d_out, int out_size, void* d_ws, size_t ws_size,
                              hipStream_t stream) {
  const float* Q = (const float*)d_in[0];
  const float* K = (const float*)d_in[1];
  const float* V = (const float*)d_in[2];
  float* O = (float*)d_out;
  const size_t elems = (size_t)BH * Ss * Dd;   // 16,777,216
  __bf16* Kb = (__bf16*)d_ws;
  __bf16* Vt = Kb + elems;

  k_prep<<<4096, 256, 0, stream>>>(K, Kb, V, Vt);
  k_flash<<<dim3((Ss / BM) * BH), 256, 0, stream>>>(Q, Kb, Vt, O);
}

// Round 7
// 348.957 us; speedup vs baseline: 1.1804x; 1.1804x over previous
//
#include <hip/hip_runtime.h>
#include <stdint.h>

// ---------- types ----------
typedef __bf16 bf16x8 __attribute__((ext_vector_type(8)));
typedef __bf16 bf16x2 __attribute__((ext_vector_type(2)));
typedef float  f32x4  __attribute__((ext_vector_type(4)));
typedef unsigned short u16x4 __attribute__((ext_vector_type(4)));
typedef unsigned short u16x8 __attribute__((ext_vector_type(8)));

#define DEVI __device__ __forceinline__

// problem constants
constexpr int Bc = 4, Hc = 16, Ss = 2048, Dd = 128;
constexpr int BH = Bc * Hc;          // 64 heads
constexpr int BM = 256;              // q-rows per workgroup (4 waves x 64), mt=4 reuse
constexpr int MT = 4;                // 16-row fragments per wave
constexpr int BN = 32;               // keys per K-tile (double-buffered)
constexpr int NTIL = Ss / BN;        // 64 tiles
// scale folds in log2(e): e^(qk/128) = 2^((qk*log2e)/128)
constexpr float SCALE = 1.44269504088896340736f / 128.0f;

constexpr int TILE_B = BN * Dd * 2;  // 8192 B
constexpr int SK_OFF = 0;            // 2 buffers x 8 KiB (K tiles, key-PERMUTED rows)
constexpr int SV_OFF = 2 * TILE_B;   // 2 buffers x 8 KiB (V^T tiles)
constexpr int LDS_BYTES = 4 * TILE_B;   // 32768 B -- sP eliminated (in-register softmax)

DEVI unsigned short f2bf_bits(float x) {
  unsigned u = __builtin_bit_cast(unsigned, x);
  u += 0x7fffu + ((u >> 16) & 1u);          // round-to-nearest-even
  return (unsigned short)(u >> 16);
}
DEVI __bf16 f2bf(float x) {
  unsigned short b = f2bf_bits(x);
  return __builtin_bit_cast(__bf16, b);
}
// pack two fp32 -> dword of 2 bf16 (compiler emits v_cvt_pk_bf16_f32)
DEVI unsigned pk2(float a, float b) {
  bf16x2 t; t[0] = (__bf16)a; t[1] = (__bf16)b;
  return __builtin_bit_cast(unsigned, t);
}

// hardware 2^x (v_exp_f32)
DEVI float exp2_hw(float x) { return __builtin_amdgcn_exp2f(x); }

// async global->LDS, 16B per lane; LDS dest = wave-uniform base + lane*16
DEVI void gload_lds16(const void* g, void* l) {
  __builtin_amdgcn_global_load_lds(
      (const __attribute__((address_space(1))) unsigned*)(uintptr_t)g,
      (__attribute__((address_space(3))) unsigned*)(unsigned)(uintptr_t)l,
      16, 0, 0);
}

// ---------------- fused pre-pass (unchanged, measured-good) ----------------
constexpr int LDT2 = 136;
__global__ void k_prep(const float* __restrict__ kin, __bf16* __restrict__ kout,
                       const float* __restrict__ v, __bf16* __restrict__ vt) {
  __shared__ __align__(16) unsigned short tile[64 * LDT2];
  const int bx = blockIdx.x;
  const int u = threadIdx.x;
  if (bx >= 2048) {
    constexpr int N4 = (BH * Ss * Dd) / 4;
    int i = (bx - 2048) * 256 + u;
    const int stride = 2048 * 256;
    #pragma unroll
    for (int it = 0; it < N4 / (2048 * 256); it++, i += stride) {
      float4 x = ((const float4*)kin)[i];
      ushort4 o;
      o.x = f2bf_bits(x.x); o.y = f2bf_bits(x.y);
      o.z = f2bf_bits(x.z); o.w = f2bf_bits(x.w);
      ((ushort4*)kout)[i] = o;
    }
    return;
  }
  const int bh = bx >> 5;
  const int s0 = (bx & 31) * 64;
  const float4* src = (const float4*)(v + ((size_t)bh * Ss + s0) * Dd);
  #pragma unroll
  for (int i = 0; i < 8; i++) {
    int f = i * 256 + u;
    int row = f >> 5;
    int c4 = (f & 31) << 2;
    float4 x = src[f];
    u16x4 o;
    o[0] = f2bf_bits(x.x); o[1] = f2bf_bits(x.y);
    o[2] = f2bf_bits(x.z); o[3] = f2bf_bits(x.w);
    *(u16x4*)&tile[row * LDT2 + c4] = o;
  }
  __syncthreads();
  const int so = u & 7;
  const int dq = u >> 3;
  u16x4 tin[8];
  #pragma unroll
  for (int i = 0; i < 8; i++)
    tin[i] = *(const u16x4*)&tile[(so * 8 + i) * LDT2 + dq * 4];
  #pragma unroll
  for (int j = 0; j < 4; j++) {
    u16x8 o;
    #pragma unroll
    for (int i = 0; i < 8; i++) o[i] = tin[i][j];
    *(u16x8*)(vt + ((size_t)bh * Dd + dq * 4 + j) * Ss + s0 + so * 8) = o;
  }
}

// ---------------- flash attention ----------------
// grid: 512 = 8 q-tiles x 64 heads; head = blockIdx%64 (same head -> same XCD).
// R5 structure (2-phase pipeline, one barrier/tile) + IN-REGISTER softmax:
// K-tile rows are staged PERMUTED so S^T slot (nt,quad,r) computes actual key
// 8*quad + 4*nt + r. Each lane's 8 exp'd scores are then exactly the keys its
// PV A-fragment needs (j = 4*nt + r) -- P never touches LDS. V^T tile layout
// already indexes k = quad*8+j, so PV contracts consistently unchanged.
__launch_bounds__(256, 2)
__global__ void k_flash(const float* __restrict__ Q, const __bf16* __restrict__ Kb,
                        const __bf16* __restrict__ Vt, float* __restrict__ O) {
  __shared__ __align__(16) char lds[LDS_BYTES];

  const int tid = threadIdx.x;
  const int w = tid >> 6;           // wave 0..3, owns q-rows [64w, 64w+64)
  const int lane = tid & 63;
  const int quad = lane >> 4;
  const int l16 = lane & 15;

  const int bx = blockIdx.x;
  const int bh = bx & (BH - 1);
  const int q0 = (bx >> 6) * BM;

  // ---- Q fragments: fp32 load, scale, cvt to bf16, keep in regs ----
  bf16x8 qa[MT][4];
  {
    const float* qb = Q + ((size_t)bh * Ss + q0 + w * 64) * Dd;
    #pragma unroll
    for (int mt = 0; mt < MT; mt++)
      #pragma unroll
      for (int kk = 0; kk < 4; kk++) {
        const float* p = qb + (mt * 16 + l16) * Dd + kk * 32 + quad * 8;
        float4 a = ((const float4*)p)[0];
        float4 b = ((const float4*)p)[1];
        bf16x8 f;
        f[0] = f2bf(a.x * SCALE); f[1] = f2bf(a.y * SCALE);
        f[2] = f2bf(a.z * SCALE); f[3] = f2bf(a.w * SCALE);
        f[4] = f2bf(b.x * SCALE); f[5] = f2bf(b.y * SCALE);
        f[6] = f2bf(b.z * SCALE); f[7] = f2bf(b.w * SCALE);
        qa[mt][kk] = f;
      }
  }

  f32x4 acc[MT][8];
  #pragma unroll
  for (int mt = 0; mt < MT; mt++)
    #pragma unroll
    for (int dt = 0; dt < 8; dt++)
      acc[mt][dt] = (f32x4){0.f, 0.f, 0.f, 0.f};

  float lacc[MT] = {0.f, 0.f, 0.f, 0.f};

  const __bf16* kbh = Kb + (size_t)bh * Ss * Dd;   // [s][d]
  const __bf16* vbh = Vt + (size_t)bh * Ss * Dd;   // [d][s]

  // ---- per-wave stage assignment: waves 0,1 -> K frags; waves 2,3 -> V frags ----
  const char* gp[4];
  unsigned lo[4];
  int ginc;
  if (w < 2) {
    // K frag (kk,nt): LDS row l16 holds actual key 8*(l16>>2) + 4*nt + (l16&3)
    #pragma unroll
    for (int i = 0; i < 4; i++) {
      const int fk = w * 4 + i, kk = fk >> 1, nt = fk & 1;
      const int key = 8 * (l16 >> 2) + 4 * nt + (l16 & 3);
      gp[i] = (const char*)(kbh + (size_t)key * Dd + kk * 32 + quad * 8);
      lo[i] = (unsigned)(SK_OFF + fk * 1024 + lane * 16);
    }
    ginc = BN * Dd * 2;             // next K tile: +32 keys
  } else {
    #pragma unroll
    for (int i = 0; i < 4; i++) {
      const int dt = (w - 2) * 4 + i;
      gp[i] = (const char*)(vbh + (size_t)(dt * 16 + l16) * Ss + quad * 8);
      lo[i] = (unsigned)(SV_OFF + dt * 1024 + lane * 16);
    }
    ginc = BN * 2;                  // next V tile: +32 columns
  }

  // ---- prologue: stage tile 0 into buffer 0 ----
  #pragma unroll
  for (int i = 0; i < 4; i++) gload_lds16(gp[i], lds + lo[i]);
  #pragma unroll
  for (int i = 0; i < 4; i++) gp[i] += ginc;
  __syncthreads();

  unsigned cur = 0;
  for (int t = 0; t < NTIL; t++) {
    // ---- issue next-tile stage FIRST (into the other buffer) ----
    if (t < NTIL - 1) {
      const unsigned nb = (cur ^ 1u) * (unsigned)TILE_B;
      #pragma unroll
      for (int i = 0; i < 4; i++) gload_lds16(gp[i], lds + lo[i] + nb);
      #pragma unroll
      for (int i = 0; i < 4; i++) gp[i] += ginc;
    }
    const char* bK = lds + SK_OFF + cur * TILE_B;
    const char* bV = lds + SV_OFF + cur * TILE_B;

    // ---- S^T = K Q^T (permuted keys) -> exp2 -> pack to registers ----
    unsigned pp[MT][4];              // packed bf16 pairs: [nt*2 + half]
    #pragma unroll
    for (int nt = 0; nt < 2; nt++) {
      f32x4 sc[MT];
      #pragma unroll
      for (int mt = 0; mt < MT; mt++) sc[mt] = (f32x4){0.f, 0.f, 0.f, 0.f};
      __builtin_amdgcn_s_setprio(1);
      #pragma unroll
      for (int kk = 0; kk < 4; kk++) {
        bf16x8 bk = *(const bf16x8*)(bK + (kk * 2 + nt) * 1024 + lane * 16);
        #pragma unroll
        for (int mt = 0; mt < MT; mt++)
          sc[mt] = __builtin_amdgcn_mfma_f32_16x16x32_bf16(bk, qa[mt][kk], sc[mt], 0, 0, 0);
      }
      __builtin_amdgcn_s_setprio(0);
      #pragma unroll
      for (int mt = 0; mt < MT; mt++) {
        float p0 = exp2_hw(sc[mt][0]);
        float p1 = exp2_hw(sc[mt][1]);
        float p2 = exp2_hw(sc[mt][2]);
        float p3 = exp2_hw(sc[mt][3]);
        lacc[mt] += (p0 + p1) + (p2 + p3);
        pp[mt][nt * 2 + 0] = pk2(p0, p1);
        pp[mt][nt * 2 + 1] = pk2(p2, p3);
      }
    }

    // ---- O += P V entirely from registers (A = pa, B = V^T frag) ----
    bf16x8 pa[MT];
    #pragma unroll
    for (int mt = 0; mt < MT; mt++) {
      uint4 u4 = make_uint4(pp[mt][0], pp[mt][1], pp[mt][2], pp[mt][3]);
      pa[mt] = __builtin_bit_cast(bf16x8, u4);
    }
    __builtin_amdgcn_s_setprio(1);
    #pragma unroll
    for (int dt = 0; dt < 8; dt++) {
      bf16x8 bv = *(const bf16x8*)(bV + dt * 1024 + lane * 16);
      #pragma unroll
      for (int mt = 0; mt < MT; mt++)
        acc[mt][dt] = __builtin_amdgcn_mfma_f32_16x16x32_bf16(pa[mt], bv, acc[mt][dt], 0, 0, 0);
    }
    __builtin_amdgcn_s_setprio(0);

    __syncthreads();    // waves done reading buf `cur`; stage of buf^1 drained here
    cur ^= 1u;
  }

  // ---- final l reduction: sum quads, broadcast to C-layout rows ----
  float inv_l[MT][4];
  #pragma unroll
  for (int mt = 0; mt < MT; mt++) {
    float l = lacc[mt];
    l += __shfl_xor(l, 16);
    l += __shfl_xor(l, 32);
    #pragma unroll
    for (int r = 0; r < 4; r++) {
      float lr = __shfl(l, (lane & 48) | (quad * 4 + r));
      inv_l[mt][r] = 1.0f / lr;
    }
  }

  // ---- epilogue: O / l ----
  float* ob = O + ((size_t)bh * Ss + q0 + w * 64) * Dd;
  #pragma unroll
  for (int mt = 0; mt < MT; mt++)
    #pragma unroll
    for (int r = 0; r < 4; r++) {
      const float inv = inv_l[mt][r];
      const int row = mt * 16 + quad * 4 + r;
      #pragma unroll
      for (int dt = 0; dt < 8; dt++)
        ob[row * Dd + dt * 16 + l16] = acc[mt][dt][r] * inv;
    }
}

extern "C" void kernel_launch(void* const* d_in, const int* in_sizes, int n_in,
                              void* d_out, int out_size, void* d_ws, size_t ws_size,
                              hipStream_t stream) {
  const float* Q = (const float*)d_in[0];
  const float* K = (const float*)d_in[1];
  const float* V = (const float*)d_in[2];
  float* O = (float*)d_out;
  const size_t elems = (size_t)BH * Ss * Dd;   // 16,777,216
  __bf16* Kb = (__bf16*)d_ws;
  __bf16* Vt = Kb + elems;

  k_prep<<<4096, 256, 0, stream>>>(K, Kb, V, Vt);
  k_flash<<<dim3((Ss / BM) * BH), 256, 0, stream>>>(Q, Kb, Vt, O);
}